// Round 11
// baseline (537.229 us; speedup 1.0000x reference)
//
#include <hip/hip_runtime.h>
#include <math.h>

#define B_   4
#define L_   1024
#define H_   768
#define NH_  12
#define E_   24
#define M_   4
#define P_   552
#define NL_  97
#define H2_  1536          // 2*H
#define HB_  49152         // H*BLK
#define R_   2208          // B*P
#define NEG_ (-1e30f)

#define RT2_  9
#define PR2_  2304         // RT2*256
#define S_    48
#define NTIL_ 7
#define KT_   1536
#define NBLK  432

typedef _Float16 h2   __attribute__((ext_vector_type(2)));
typedef _Float16 f16x8 __attribute__((ext_vector_type(8)));
typedef float    f32x4 __attribute__((ext_vector_type(4)));

__device__ inline uint pkh(float lo, float hi) {
    union { __fp16 v __attribute__((ext_vector_type(2))); uint u; } c;
    c.v = __builtin_amdgcn_cvt_pkrtz(lo, hi);
    return c.u;
}
__device__ inline ushort h_rne(float x) {
    union { _Float16 h; ushort u; } c; c.h = (_Float16)x; return c.u;
}
__device__ inline uint h2_rne(float lo, float hi) {
    return (uint)h_rne(lo) | ((uint)h_rne(hi) << 16);
}

// device-wide barrier: per-phase counter, agent-scope atomics (cross-XCD safe)
__device__ inline void gridbar(uint* ctr) {
    __syncthreads();
    if (threadIdx.x == 0) {
        __threadfence();   // release: flush this block's writes to coherence point
        __hip_atomic_fetch_add(ctr, 1u, __ATOMIC_ACQ_REL, __HIP_MEMORY_SCOPE_AGENT);
        while (__hip_atomic_load(ctr, __ATOMIC_ACQUIRE, __HIP_MEMORY_SCOPE_AGENT) < (uint)NBLK)
            __builtin_amdgcn_s_sleep(8);
        __threadfence();   // acquire: invalidate stale local caches
    }
    __syncthreads();
}

__global__ void k_init(uint* bar) {
    if (threadIdx.x < 96) bar[threadIdx.x] = 0u;
}

// pack segment bounds
#define PKB_ATT 1152
#define PKB_WB2 672
#define PKB_W2  288
#define PKB_SEQ 1536
#define PKB_EMB 96
#define PKB_TOT (PKB_ATT + PKB_WB2 + PKB_W2 + PKB_SEQ + PKB_EMB)
#define LDSTR   516

__launch_bounds__(256, 2)
__global__ void k_mega(const float* __restrict__ att, const float* __restrict__ Wb,
                       const float* __restrict__ Wh, const float* __restrict__ Wt,
                       const float* __restrict__ seq,
                       const int* __restrict__ midx, const float* __restrict__ mmask,
                       const float* __restrict__ bh, const float* __restrict__ bt,
                       const float* __restrict__ bb, const int* __restrict__ hts,
                       _Float16* __restrict__ ea, _Float16* __restrict__ WbP,
                       _Float16* __restrict__ WhP, _Float16* __restrict__ WtP,
                       _Float16* __restrict__ seqP, _Float16* __restrict__ ee,
                       _Float16* __restrict__ ht, _Float16* __restrict__ rs,
                       _Float16* __restrict__ zh, _Float16* __restrict__ zt,
                       _Float16* __restrict__ part, float* __restrict__ out,
                       uint* __restrict__ bar) {
    __shared__ __align__(16) char smem[47104];
    __shared__ float red2[2][2];
    int blk = blockIdx.x, tid = threadIdx.x;

    // ---------------- phase 1: pack (grid-stride over 3744 units) ----------
    {
        float (*lds)[LDSTR] = (float(*)[LDSTR])smem;
        for (int u = blk; u < PKB_TOT; u += NBLK) {
            __syncthreads();                 // LDS reuse guard across units
            int bid = u;
            if (bid < PKB_ATT) {
                int n  = bid % NH_;
                int be = bid / NH_;
                int b  = be / E_;
                int idx[M_]; float msk[M_]; float denom = 0.f;
#pragma unroll
                for (int m = 0; m < M_; ++m) { idx[m] = midx[be*M_+m]; msk[m] = mmask[be*M_+m]; denom += msk[m]; }
                float inv = 1.f / denom;
                const float* abase = att + (size_t)(b*NH_ + n) * L_ * L_;
                int l4 = tid * 4;
                float s0 = 0.f, s1 = 0.f, s2 = 0.f, s3 = 0.f;
#pragma unroll
                for (int m = 0; m < M_; ++m) {
                    float4 a = *(const float4*)(abase + idx[m]*L_ + l4);
                    s0 += msk[m]*a.x; s1 += msk[m]*a.y; s2 += msk[m]*a.z; s3 += msk[m]*a.w;
                }
                *(uint2*)(ea + (((size_t)(be*NH_ + n)) << 10) + l4) =
                    make_uint2(pkh(s0*inv, s1*inv), pkh(s2*inv, s3*inv));
            } else if (bid < PKB_ATT + PKB_WB2 + PKB_W2) {
                int seg = bid - PKB_ATT;
                const float* W; _Float16* WP; int nt, kb, N16, Nvalid, Kdim;
                if (seg < PKB_WB2) {
                    W = Wb; WP = WbP; N16 = 7; Nvalid = NL_; Kdim = HB_;
                    nt = seg % 7; kb = seg / 7;
                } else {
                    int s2 = seg - PKB_WB2;
                    int which = s2 / 144;
                    int s = s2 % 144;
                    W = which ? Wt : Wh; WP = which ? WtP : WhP;
                    N16 = 48; Nvalid = H_; Kdim = H2_;
                    nt = s % 48; kb = s / 48;
                }
                int k0 = kb * 512;
#pragma unroll
                for (int it = 0; it < 8; ++it) {
                    int f4 = tid + it*256;
                    int row = f4 >> 7;
                    int c4  = (f4 & 127) << 2;
                    int n   = nt*16 + row;
                    float4 v = make_float4(0.f,0.f,0.f,0.f);
                    if (n < Nvalid) v = *(const float4*)(W + (size_t)n*Kdim + k0 + c4);
                    *(float4*)&lds[row][c4] = v;
                }
                __syncthreads();
                int kt0 = kb * 16;
#pragma unroll
                for (int it = 0; it < 4; ++it) {
                    int fi = tid + it*256;
                    int kt_l = fi >> 6, lane = fi & 63;
                    int n_l = lane & 15;
                    int k_l = kt_l*32 + ((lane >> 4) << 3);
                    float4 a = *(const float4*)&lds[n_l][k_l];
                    float4 b = *(const float4*)&lds[n_l][k_l + 4];
                    uint4 w = make_uint4(h2_rne(a.x,a.y), h2_rne(a.z,a.w),
                                         h2_rne(b.x,b.y), h2_rne(b.z,b.w));
                    *(uint4*)(WP + (((size_t)(kt0 + kt_l)*N16 + nt) << 9) + lane*8) = w;
                }
            } else if (bid < PKB_ATT + PKB_WB2 + PKB_W2 + PKB_SEQ) {
                int t = (bid - PKB_ATT - PKB_WB2 - PKB_W2)*256 + tid;
                int lane = t & 63;
                int rest = t >> 6;
                int nt = rest % 48; rest /= 48;
                int kt = rest % 32;
                int b  = rest / 32;
                int n = nt*16 + (lane & 15);
                int k = kt*32 + ((lane >> 4) << 3);
                const float* src = seq + ((size_t)(b*L_ + k))*H_ + n;
                uint w[4];
#pragma unroll
                for (int e = 0; e < 4; ++e) w[e] = h2_rne(src[(2*e)*H_], src[(2*e+1)*H_]);
                *(uint4*)(seqP + (size_t)t*8) = make_uint4(w[0],w[1],w[2],w[3]);
            } else {
                int be = bid - (PKB_ATT + PKB_WB2 + PKB_W2 + PKB_SEQ);
                int b  = be / E_;
                int idx[M_]; float msk[M_];
#pragma unroll
                for (int m = 0; m < M_; ++m) { idx[m] = midx[be*M_+m]; msk[m] = mmask[be*M_+m]; }
                for (int d = tid; d < H_; d += 256) {
                    float v[M_]; float mx = NEG_;
#pragma unroll
                    for (int m = 0; m < M_; ++m) {
                        v[m] = (msk[m] > 0.f) ? seq[(b*L_ + idx[m])*H_ + d] : NEG_;
                        mx = fmaxf(mx, v[m]);
                    }
                    float s = 0.f;
#pragma unroll
                    for (int m = 0; m < M_; ++m) s += expf(v[m] - mx);
                    ee[be*H_ + d] = (_Float16)(mx + logf(s));
                }
            }
        }
    }
    gridbar(bar + 0);

    // ---------------- phase 2: ht_att (2 pairs per block, 1104 units) ------
    {
        int half = tid >> 7, t128 = tid & 127;
        for (int u = blk; u < 1104; u += NBLK) {
            int bp = u*2 + half;
            int b  = bp / P_;
            int h = hts[bp*2+0], t = hts[bp*2+1];
            const uint4* eh4 = (const uint4*)(ea + ((size_t)(b*E_ + h)*NH_ << 10));
            const uint4* et4 = (const uint4*)(ea + ((size_t)(b*E_ + t)*NH_ << 10));
            float s[8] = {};
#pragma unroll
            for (int n = 0; n < NH_; ++n) {
                union { uint4 u4; h2 v[4]; } A, C;
                A.u4 = eh4[n*128 + t128];
                C.u4 = et4[n*128 + t128];
#pragma unroll
                for (int q = 0; q < 4; ++q) {
                    s[2*q]   += (float)A.v[q][0]*(float)C.v[q][0];
                    s[2*q+1] += (float)A.v[q][1]*(float)C.v[q][1];
                }
            }
            float local = 0.f;
#pragma unroll
            for (int q = 0; q < 8; ++q) { s[q] *= (1.f/NH_); local += s[q]; }
#pragma unroll
            for (int o = 32; o > 0; o >>= 1) local += __shfl_down(local, o);
            int wid2 = t128 >> 6, lane = tid & 63;
            if (lane == 0) red2[half][wid2] = local;
            __syncthreads();
            if (t128 == 0) red2[half][0] = 1.f / (red2[half][0] + red2[half][1] + 1e-5f);
            __syncthreads();
            float inv = red2[half][0];
            *(uint4*)(ht + ((size_t)bp << 10) + t128*8) =
                make_uint4(pkh(s[0]*inv, s[1]*inv), pkh(s[2]*inv, s[3]*inv),
                           pkh(s[4]*inv, s[5]*inv), pkh(s[6]*inv, s[7]*inv));
            __syncthreads();
        }
    }
    gridbar(bar + 16);

    // ---------------- phase 3: rs (240 blocks) -----------------------------
    if (blk < 240) {
        _Float16* as = (_Float16*)smem;
        int xcd = blk & 7, jj0 = blk >> 3;
        int b    = xcd >> 1;
        int tile = (xcd & 1)*30 + jj0;
        int p0   = (tile % 5) * 128;
        int nt0  = (tile / 5) * 4;
        int wave = tid >> 6, lane = tid & 63;

        const _Float16* srcp[4];
        int ldst[4];
#pragma unroll
        for (int i = 0; i < 4; ++i) {
            int t = tid + i*256;
            int row = t >> 3, c8 = (t & 7)*8;
            int p = p0 + row;
            srcp[i] = (p < P_) ? ht + (((size_t)(b*P_ + p)) << 10) + c8 : nullptr;
            ldst[i] = row*72 + c8;
        }
        uint4 st[4];
#pragma unroll
        for (int i = 0; i < 4; ++i)
            st[i] = srcp[i] ? *(const uint4*)(srcp[i]) : make_uint4(0,0,0,0);

        f32x4 acc[2][4] = {};
        const _Float16* wbase = seqP + ((size_t)b*32*48 + nt0)*512 + lane*8;
        int rowbase = wave*32 + (lane & 15);
        int asub = (lane >> 4) << 3;

        for (int kc = 0; kc < 16; ++kc) {
            if (kc) __syncthreads();
#pragma unroll
            for (int i = 0; i < 4; ++i) *(uint4*)(as + ldst[i]) = st[i];
            __syncthreads();
            if (kc + 1 < 16) {
#pragma unroll
                for (int i = 0; i < 4; ++i)
                    st[i] = srcp[i] ? *(const uint4*)(srcp[i] + (kc+1)*64) : make_uint4(0,0,0,0);
            }
#pragma unroll
            for (int kk = 0; kk < 2; ++kk) {
                int kt = kc*2 + kk;
                const _Float16* wp = wbase + (size_t)kt*(48*512);
                f16x8 bf[4];
#pragma unroll
                for (int jn = 0; jn < 4; ++jn) bf[jn] = *(const f16x8*)(wp + jn*512);
#pragma unroll
                for (int ms = 0; ms < 2; ++ms) {
                    f16x8 af = *(const f16x8*)(as + (rowbase + ms*16)*72 + kk*32 + asub);
#pragma unroll
                    for (int jn = 0; jn < 4; ++jn)
                        acc[ms][jn] = __builtin_amdgcn_mfma_f32_16x16x32_f16(af, bf[jn], acc[ms][jn], 0, 0, 0);
                }
            }
        }
        int crow = (lane >> 4) * 4;
        int ccol = lane & 15;
#pragma unroll
        for (int ms = 0; ms < 2; ++ms) {
#pragma unroll
            for (int jn = 0; jn < 4; ++jn) {
                int n = nt0*16 + jn*16 + ccol;
#pragma unroll
                for (int reg = 0; reg < 4; ++reg) {
                    int p = p0 + wave*32 + ms*16 + crow + reg;
                    if (p < P_) rs[(size_t)(b*P_ + p)*H_ + n] = (_Float16)acc[ms][jn][reg];
                }
            }
        }
    }
    gridbar(bar + 32);

    // ---------------- phase 4: z (432 blocks) ------------------------------
    {
        _Float16* as = (_Float16*)smem;
        int xcd = blk & 7, jj0 = blk >> 3;
        int which = xcd >> 2;
        int tile  = (xcd & 3)*54 + jj0;
        int r0  = (tile % 18) * 128;
        int nt0 = (tile / 18) * 4;
        const _Float16* WP   = which ? WtP : WhP;
        const float*    bias = which ? bt  : bh;
        _Float16*       outz = which ? zt  : zh;
        int wave = tid >> 6, lane = tid & 63;

        const _Float16* srcA[4];
        const _Float16* srcB[4];
        int ldst[4];
#pragma unroll
        for (int i = 0; i < 4; ++i) {
            int t = tid + i*256;
            int row = t >> 3, c8 = (t & 7)*8;
            int r = r0 + row;
            if (r < R_) {
                int b = r / P_;
                int eidx = hts[r*2 + which];
                srcA[i] = ee + (size_t)(b*E_ + eidx)*H_ + c8;
                srcB[i] = rs + (size_t)r*H_ + c8;
            } else { srcA[i] = nullptr; srcB[i] = nullptr; }
            ldst[i] = row*72 + c8;
        }
        uint4 st[4];
#pragma unroll
        for (int i = 0; i < 4; ++i)
            st[i] = srcA[i] ? *(const uint4*)(srcA[i]) : make_uint4(0,0,0,0);

        f32x4 acc[2][4] = {};
        const _Float16* wbase = WP + (size_t)nt0*512 + lane*8;
        int rowbase = wave*32 + (lane & 15);
        int asub = (lane >> 4) << 3;

        for (int kc = 0; kc < 24; ++kc) {
            if (kc) __syncthreads();
#pragma unroll
            for (int i = 0; i < 4; ++i) *(uint4*)(as + ldst[i]) = st[i];
            __syncthreads();
            if (kc + 1 < 24) {
                int kn = kc + 1;
#pragma unroll
                for (int i = 0; i < 4; ++i) {
                    const _Float16* s = (kn < 12) ? (srcA[i] ? srcA[i] + kn*64 : nullptr)
                                                  : (srcB[i] ? srcB[i] + (kn-12)*64 : nullptr);
                    st[i] = s ? *(const uint4*)s : make_uint4(0,0,0,0);
                }
            }
#pragma unroll
            for (int kk = 0; kk < 2; ++kk) {
                int kt = kc*2 + kk;
                const _Float16* wp = wbase + (size_t)kt*(48*512);
                f16x8 bf[4];
#pragma unroll
                for (int jn = 0; jn < 4; ++jn) bf[jn] = *(const f16x8*)(wp + jn*512);
#pragma unroll
                for (int ms = 0; ms < 2; ++ms) {
                    f16x8 af = *(const f16x8*)(as + (rowbase + ms*16)*72 + kk*32 + asub);
#pragma unroll
                    for (int jn = 0; jn < 4; ++jn)
                        acc[ms][jn] = __builtin_amdgcn_mfma_f32_16x16x32_f16(af, bf[jn], acc[ms][jn], 0, 0, 0);
                }
            }
        }
        int crow = (lane >> 4) * 4;
        int ccol = lane & 15;
#pragma unroll
        for (int ms = 0; ms < 2; ++ms) {
#pragma unroll
            for (int jn = 0; jn < 4; ++jn) {
                int n = nt0*16 + jn*16 + ccol;
                float bv = bias[n];
#pragma unroll
                for (int reg = 0; reg < 4; ++reg) {
                    int r = r0 + wave*32 + ms*16 + crow + reg;
                    if (r < R_) outz[(size_t)r*H_ + n] = (_Float16)tanhf(acc[ms][jn][reg] + bv);
                }
            }
        }
    }
    gridbar(bar + 48);

    // ---------------- phase 5: logits (432 blocks) -------------------------
    {
        _Float16* zhs = (_Float16*)smem;            // 256*20
        _Float16* zts = zhs + 256*20;               // 256*72
        int xcd = blk & 7, j = blk >> 3;
        int kc  = xcd*6 + j/9;
        int rt  = j % 9;
        int r0  = rt * 256;
        int g64 = (kc >> 2) * 64;
        int a0  = (kc & 3) * 16;

        for (int it = 0; it < 2; ++it) {
            int t = tid + it*256;
            int row = t >> 1, i8 = (t & 1)*8;
            int r = r0 + row;
            uint4 w = make_uint4(0,0,0,0);
            if (r < R_) w = *(const uint4*)(zh + (size_t)r*H_ + g64 + a0 + i8);
            *(uint4*)(zhs + row*20 + i8) = w;
        }
        for (int it = 0; it < 8; ++it) {
            int t = tid + it*256;
            int row = t >> 3, j8 = (t & 7)*8;
            int r = r0 + row;
            uint4 w = make_uint4(0,0,0,0);
            if (r < R_) w = *(const uint4*)(zt + (size_t)r*H_ + g64 + j8);
            *(uint4*)(zts + row*72 + j8) = w;
        }
        __syncthreads();

        int wave = tid >> 6, lane = tid & 63;
        int rowA0 = wave*64 + (lane & 15);
        int jsub  = (lane >> 4) * 8;

        f32x4 acc[4][NTIL_] = {};
        const _Float16* wb0 = WbP + (size_t)(kc*32) * (NTIL_*512) + lane*8;

        f16x8 bf[NTIL_];
#pragma unroll
        for (int nt = 0; nt < NTIL_; ++nt) bf[nt] = *(const f16x8*)(wb0 + nt*512);

        for (int ktl = 0; ktl < 32; ++ktl) {
            f16x8 bn[NTIL_];
            if (ktl + 1 < 32) {
                const _Float16* wp = wb0 + (size_t)(ktl+1) * (NTIL_*512);
#pragma unroll
                for (int nt = 0; nt < NTIL_; ++nt) bn[nt] = *(const f16x8*)(wp + nt*512);
            }
            int il = ktl >> 1;
            int jb = (ktl & 1) * 32 + jsub;
#pragma unroll
            for (int ms = 0; ms < 4; ++ms) {
                int row = rowA0 + ms*16;
                _Float16 hv = zhs[row*20 + il];
                h2 hb = {hv, hv};
                union { uint4 u4; h2 v[4]; } T;
                T.u4 = *(const uint4*)(zts + row*72 + jb);
                union { h2 v[4]; f16x8 f; } A;
                A.v[0] = hb * T.v[0];
                A.v[1] = hb * T.v[1];
                A.v[2] = hb * T.v[2];
                A.v[3] = hb * T.v[3];
#pragma unroll
                for (int nt = 0; nt < NTIL_; ++nt)
                    acc[ms][nt] = __builtin_amdgcn_mfma_f32_16x16x32_f16(A.f, bf[nt], acc[ms][nt], 0, 0, 0);
            }
            if (ktl + 1 < 32) {
#pragma unroll
                for (int nt = 0; nt < NTIL_; ++nt) bf[nt] = bn[nt];
            }
        }

        int crow0 = wave*64 + (lane >> 4) * 4;
        int ccol  = lane & 15;
#pragma unroll
        for (int ms = 0; ms < 4; ++ms) {
#pragma unroll
            for (int nt = 0; nt < NTIL_; ++nt) {
#pragma unroll
                for (int reg = 0; reg < 4; ++reg) {
                    int rp = r0 + crow0 + ms*16 + reg;
                    part[((size_t)kc*PR2_ + rp)*112 + nt*16 + ccol] = (_Float16)acc[ms][nt][reg];
                }
            }
        }
    }
    gridbar(bar + 64);

    // ---------------- phase 6: reduce (grid-stride) ------------------------
    for (int idx = blk*256 + tid; idx < R_*NL_; idx += NBLK*256) {
        int r = idx / NL_, n = idx - r*NL_;
        float s = bb[n];
#pragma unroll
        for (int kc = 0; kc < S_; ++kc) s += (float)part[((size_t)kc*PR2_ + r)*112 + n];
        out[idx] = s;
    }
}

extern "C" void kernel_launch(void* const* d_in, const int* in_sizes, int n_in,
                              void* d_out, int out_size, void* d_ws, size_t ws_size,
                              hipStream_t stream) {
    const float* seq   = (const float*)d_in[0];
    const float* att   = (const float*)d_in[1];
    const float* mmask = (const float*)d_in[2];
    const float* Wh    = (const float*)d_in[3];
    const float* bh    = (const float*)d_in[4];
    const float* Wt    = (const float*)d_in[5];
    const float* bt    = (const float*)d_in[6];
    const float* Wb    = (const float*)d_in[7];
    const float* bb    = (const float*)d_in[8];
    const int*   midx  = (const int*)d_in[9];
    const int*   hts   = (const int*)d_in[10];
    float* out = (float*)d_out;

    char* base = (char*)d_ws;
    _Float16* WbP  = (_Float16*)base;  base += (size_t)KT_*NTIL_*64*8 * 2;
    _Float16* WhP  = (_Float16*)base;  base += (size_t)48*48*64*8 * 2;
    _Float16* WtP  = (_Float16*)base;  base += (size_t)48*48*64*8 * 2;
    _Float16* seqP = (_Float16*)base;  base += (size_t)B_*32*48*64*8 * 2;
    _Float16* ee   = (_Float16*)base;  base += (size_t)B_*E_*H_ * 2;
    _Float16* ea   = (_Float16*)base;  base += (size_t)B_*E_*NH_*L_ * 2;
    _Float16* ht   = (_Float16*)base;  base += (size_t)R_*L_ * 2;
    _Float16* rs   = (_Float16*)base;  base += (size_t)R_*H_ * 2;
    _Float16* zh   = (_Float16*)base;  base += (size_t)R_*H_ * 2;
    _Float16* zt   = (_Float16*)base;  base += (size_t)R_*H_ * 2;
    _Float16* part = (_Float16*)base;  base += (size_t)S_*PR2_*112 * 2;
    uint*     bar  = (uint*)base;

    k_init<<<dim3(1), dim3(96), 0, stream>>>(bar);
    k_mega<<<dim3(NBLK), dim3(256), 0, stream>>>(
        att, Wb, Wh, Wt, seq, midx, mmask, bh, bt, bb, hts,
        ea, WbP, WhP, WtP, seqP, ee, ht, rs, zh, zt, part, out, bar);
}

// Round 12
// 120.249 us; speedup vs baseline: 4.4677x; 4.4677x over previous
//
#include <hip/hip_runtime.h>
#include <math.h>

#define B_   4
#define L_   1024
#define H_   768
#define NH_  12
#define E_   24
#define M_   4
#define P_   552
#define NL_  97
#define H2_  1536          // 2*H
#define HB_  49152         // H*BLK
#define R_   2208          // B*P
#define NEG_ (-1e30f)

// logits MFMA tiling: BM=256 (4 waves x ms=4), 9 r-tiles, 48 K-chunks of 1024
#define RT2_  9
#define PR2_  2304         // RT2*256
#define S_    48
#define NTIL_ 7            // 112 padded cols / 16
#define KT_   1536         // HB/32 k-steps total

typedef _Float16 h2   __attribute__((ext_vector_type(2)));
typedef _Float16 f16x8 __attribute__((ext_vector_type(8)));
typedef float    f32x4 __attribute__((ext_vector_type(4)));

__device__ inline uint pkh(float lo, float hi) {      // fast RTZ pack
    union { __fp16 v __attribute__((ext_vector_type(2))); uint u; } c;
    c.v = __builtin_amdgcn_cvt_pkrtz(lo, hi);
    return c.u;
}
__device__ inline ushort h_rne(float x) {
    union { _Float16 h; ushort u; } c; c.h = (_Float16)x; return c.u;
}
__device__ inline uint h2_rne(float lo, float hi) {
    return (uint)h_rne(lo) | ((uint)h_rne(hi) << 16);
}

// ---------------- fused pack + ent_att + ent_emb (round-9 proven) ----------
#define PKB_ATT 1152
#define PKB_WB  2688
#define PKB_W   576      // 48kt*48nt*64lane = 147456 = 576*256 EXACT
#define PKB_SEQ 1536
#define PKB_EMB 96
__global__ void k_pack(const float* __restrict__ att, const float* __restrict__ Wb,
                       const float* __restrict__ Wh, const float* __restrict__ Wt,
                       const float* __restrict__ seq,
                       const int* __restrict__ midx, const float* __restrict__ mmask,
                       _Float16* __restrict__ ea, _Float16* __restrict__ WbP,
                       _Float16* __restrict__ WhP, _Float16* __restrict__ WtP,
                       _Float16* __restrict__ seqP, _Float16* __restrict__ ee) {
    int bid = blockIdx.x;
    if (bid < PKB_ATT) {                    // entity_atts -> fp16 (float4 loads)
        int n  = bid % NH_;
        int be = bid / NH_;
        int b  = be / E_;
        int idx[M_]; float msk[M_]; float denom = 0.f;
#pragma unroll
        for (int m = 0; m < M_; ++m) { idx[m] = midx[be*M_+m]; msk[m] = mmask[be*M_+m]; denom += msk[m]; }
        float inv = 1.f / denom;
        const float* abase = att + (size_t)(b*NH_ + n) * L_ * L_;
        int l4 = threadIdx.x * 4;
        float s0 = 0.f, s1 = 0.f, s2 = 0.f, s3 = 0.f;
#pragma unroll
        for (int m = 0; m < M_; ++m) {
            float4 a = *(const float4*)(abase + idx[m]*L_ + l4);
            s0 += msk[m]*a.x; s1 += msk[m]*a.y; s2 += msk[m]*a.z; s3 += msk[m]*a.w;
        }
        *(uint2*)(ea + (((size_t)(be*NH_ + n)) << 10) + l4) =
            make_uint2(pkh(s0*inv, s1*inv), pkh(s2*inv, s3*inv));
        return;
    }
    if (bid < PKB_ATT + PKB_WB) {           // Wb -> [kt][nt][lane][8]
        int t = (bid - PKB_ATT)*256 + threadIdx.x;
        int lane = t & 63;
        int nt   = (t >> 6) % NTIL_;
        int kt   = t / (NTIL_*64);
        int n = nt*16 + (lane & 15);
        int k = kt*32 + ((lane >> 4) << 3);
        uint w[4] = {0u,0u,0u,0u};
        if (n < NL_) {
            const float* src = Wb + (size_t)n*HB_ + k;
#pragma unroll
            for (int e = 0; e < 4; ++e) w[e] = h2_rne(src[2*e], src[2*e+1]);
        }
        *(uint4*)(WbP + (size_t)t*8) = make_uint4(w[0],w[1],w[2],w[3]);
        return;
    }
    if (bid < PKB_ATT + PKB_WB + 2*PKB_W) { // Wh / Wt -> [kt][nt][lane][8]
        int seg = bid - PKB_ATT - PKB_WB;
        const float* W = (seg < PKB_W) ? Wh : Wt;
        _Float16*   WP = (seg < PKB_W) ? WhP : WtP;
        int t = (seg % PKB_W)*256 + threadIdx.x;
        int lane = t & 63;
        int nt   = (t >> 6) % 48;
        int kt   = t / (48*64);
        int n = nt*16 + (lane & 15);
        int k = kt*32 + ((lane >> 4) << 3);
        const float* src = W + (size_t)n*H2_ + k;
        uint w[4];
#pragma unroll
        for (int e = 0; e < 4; ++e) w[e] = h2_rne(src[2*e], src[2*e+1]);
        *(uint4*)(WP + (size_t)t*8) = make_uint4(w[0],w[1],w[2],w[3]);
        return;
    }
    if (bid < PKB_ATT + PKB_WB + 2*PKB_W + PKB_SEQ) {   // seq -> per-b frag
        int t = (bid - PKB_ATT - PKB_WB - 2*PKB_W)*256 + threadIdx.x;
        int lane = t & 63;
        int rest = t >> 6;
        int nt = rest % 48; rest /= 48;
        int kt = rest % 32;
        int b  = rest / 32;
        int n = nt*16 + (lane & 15);
        int k = kt*32 + ((lane >> 4) << 3);
        const float* src = seq + ((size_t)(b*L_ + k))*H_ + n;
        uint w[4];
#pragma unroll
        for (int e = 0; e < 4; ++e) w[e] = h2_rne(src[(2*e)*H_], src[(2*e+1)*H_]);
        *(uint4*)(seqP + (size_t)t*8) = make_uint4(w[0],w[1],w[2],w[3]);
        return;
    }
    // ent_emb: logsumexp over mentions -> fp16
    int be = bid - (PKB_ATT + PKB_WB + 2*PKB_W + PKB_SEQ);
    int b  = be / E_;
    int idx[M_]; float msk[M_];
#pragma unroll
    for (int m = 0; m < M_; ++m) { idx[m] = midx[be*M_+m]; msk[m] = mmask[be*M_+m]; }
    for (int d = threadIdx.x; d < H_; d += 256) {
        float v[M_]; float mx = NEG_;
#pragma unroll
        for (int m = 0; m < M_; ++m) {
            v[m] = (msk[m] > 0.f) ? seq[(b*L_ + idx[m])*H_ + d] : NEG_;
            mx = fmaxf(mx, v[m]);
        }
        float s = 0.f;
#pragma unroll
        for (int m = 0; m < M_; ++m) s += expf(v[m] - mx);
        ee[be*H_ + d] = (_Float16)(mx + logf(s));
    }
}

// ---------------- K3: ht_att (128 threads, 16B loads) ----------------------
__global__ void k_ht_att(const _Float16* __restrict__ ea, const int* __restrict__ hts,
                         _Float16* __restrict__ ht) {
    __shared__ float red[2];
    int bp = blockIdx.x;            // b*P+p
    int b  = bp / P_;
    int h = hts[bp*2+0], t = hts[bp*2+1];
    const uint4* eh4 = (const uint4*)(ea + ((size_t)(b*E_ + h)*NH_ << 10));
    const uint4* et4 = (const uint4*)(ea + ((size_t)(b*E_ + t)*NH_ << 10));
    int lp = threadIdx.x;           // 0..127, each covers l = lp*8..+7
    float s[8] = {};
#pragma unroll
    for (int n = 0; n < NH_; ++n) {
        union { uint4 u; h2 v[4]; } A, C;
        A.u = eh4[n*128 + lp];
        C.u = et4[n*128 + lp];
#pragma unroll
        for (int q = 0; q < 4; ++q) {
            s[2*q]   += (float)A.v[q][0]*(float)C.v[q][0];
            s[2*q+1] += (float)A.v[q][1]*(float)C.v[q][1];
        }
    }
    float local = 0.f;
#pragma unroll
    for (int q = 0; q < 8; ++q) { s[q] *= (1.f/NH_); local += s[q]; }
#pragma unroll
    for (int o = 32; o > 0; o >>= 1) local += __shfl_down(local, o);
    int wid = threadIdx.x >> 6, lane = threadIdx.x & 63;
    if (lane == 0) red[wid] = local;
    __syncthreads();
    if (threadIdx.x == 0) red[0] = 1.f / (red[0] + red[1] + 1e-5f);
    __syncthreads();
    float inv = red[0];
    *(uint4*)(ht + ((size_t)bp << 10) + lp*8) =
        make_uint4(pkh(s[0]*inv, s[1]*inv), pkh(s[2]*inv, s[3]*inv),
                   pkh(s[4]*inv, s[5]*inv), pkh(s[6]*inv, s[7]*inv));
}

// ---------------- K4: rs = ht @ seq, BM=128 (ms=2), XCD-pinned b -----------
__launch_bounds__(256, 2)
__global__ void k_rs_mfma(const _Float16* __restrict__ ht, const _Float16* __restrict__ seqP,
                          _Float16* __restrict__ rs) {
    __shared__ _Float16 as[128*72];
    int bid = blockIdx.x;
    int xcd = bid & 7, jj0 = bid >> 3;   // jj0 0..29
    int b    = xcd >> 1;
    int tile = (xcd & 1)*30 + jj0;       // 0..59
    int p0   = (tile % 5) * 128;
    int nt0  = (tile / 5) * 4;
    int wave = threadIdx.x >> 6, lane = threadIdx.x & 63;

    const _Float16* srcp[4];
    int ldst[4];
#pragma unroll
    for (int i = 0; i < 4; ++i) {
        int t = threadIdx.x + i*256;
        int row = t >> 3, c8 = (t & 7)*8;
        int p = p0 + row;
        srcp[i] = (p < P_) ? ht + (((size_t)(b*P_ + p)) << 10) + c8 : nullptr;
        ldst[i] = row*72 + c8;
    }
    uint4 st[4];
#pragma unroll
    for (int i = 0; i < 4; ++i)
        st[i] = srcp[i] ? *(const uint4*)(srcp[i]) : make_uint4(0,0,0,0);

    f32x4 acc[2][4] = {};
    const _Float16* wbase = seqP + ((size_t)b*32*48 + nt0)*512 + lane*8;
    int rowbase = wave*32 + (lane & 15);
    int asub = (lane >> 4) << 3;

    for (int kc = 0; kc < 16; ++kc) {
        if (kc) __syncthreads();
#pragma unroll
        for (int i = 0; i < 4; ++i) *(uint4*)(as + ldst[i]) = st[i];
        __syncthreads();
        if (kc + 1 < 16) {
#pragma unroll
            for (int i = 0; i < 4; ++i)
                st[i] = srcp[i] ? *(const uint4*)(srcp[i] + (kc+1)*64) : make_uint4(0,0,0,0);
        }
#pragma unroll
        for (int kk = 0; kk < 2; ++kk) {
            int kt = kc*2 + kk;
            const _Float16* wp = wbase + (size_t)kt*(48*512);
            f16x8 bf[4];
#pragma unroll
            for (int jn = 0; jn < 4; ++jn) bf[jn] = *(const f16x8*)(wp + jn*512);
#pragma unroll
            for (int ms = 0; ms < 2; ++ms) {
                f16x8 af = *(const f16x8*)(as + (rowbase + ms*16)*72 + kk*32 + asub);
#pragma unroll
                for (int jn = 0; jn < 4; ++jn)
                    acc[ms][jn] = __builtin_amdgcn_mfma_f32_16x16x32_f16(af, bf[jn], acc[ms][jn], 0, 0, 0);
            }
        }
    }
    int crow = (lane >> 4) * 4;
    int ccol = lane & 15;
#pragma unroll
    for (int ms = 0; ms < 2; ++ms) {
#pragma unroll
        for (int jn = 0; jn < 4; ++jn) {
            int n = nt0*16 + jn*16 + ccol;
#pragma unroll
            for (int reg = 0; reg < 4; ++reg) {
                int p = p0 + wave*32 + ms*16 + crow + reg;
                if (p < P_) rs[(size_t)(b*P_ + p)*H_ + n] = (_Float16)acc[ms][jn][reg];
            }
        }
    }
}

// ---------------- K5: zh & zt FUSED — BM=128, 512 thr (8 waves), grid 216 --
// tile = xcd*27 + (bid>>3): rt = tile%18, nt = tile/18 (per-XCD weight ~0.8MB)
// kc<12: A = gathered ee (h for zh, t for zt, separate LDS); kc>=12: A = rs SHARED
__launch_bounds__(512, 2)
__global__ void k_z_mfma(const _Float16* __restrict__ ee, const _Float16* __restrict__ rs,
                         const _Float16* __restrict__ WhP, const _Float16* __restrict__ WtP,
                         const float* __restrict__ bh, const float* __restrict__ bt,
                         const int* __restrict__ hts,
                         _Float16* __restrict__ zh, _Float16* __restrict__ zt) {
    __shared__ _Float16 as0[128*72];   // 18 KB (zh A / shared rs)
    __shared__ _Float16 as1[128*72];   // 18 KB (zt A, kc<12 only)
    int bid = blockIdx.x;
    int xcd = bid & 7, j = bid >> 3;   // j 0..26
    int tile = xcd*27 + j;             // 0..215
    int r0  = (tile % 18) * 128;
    int nt0 = (tile / 18) * 4;
    int tid = threadIdx.x;
    int wave = tid >> 6, lane = tid & 63;

    const _Float16* srcA0[2];
    const _Float16* srcA1[2];
    const _Float16* srcB[2];
    int ldst[2];
#pragma unroll
    for (int i = 0; i < 2; ++i) {
        int t = tid + i*512;
        int row = t >> 3, c8 = (t & 7)*8;
        int r = r0 + row;
        if (r < R_) {
            int b = r / P_;
            int e0 = hts[r*2+0], e1 = hts[r*2+1];
            srcA0[i] = ee + (size_t)(b*E_ + e0)*H_ + c8;
            srcA1[i] = ee + (size_t)(b*E_ + e1)*H_ + c8;
            srcB[i]  = rs + (size_t)r*H_ + c8;
        } else { srcA0[i] = nullptr; srcA1[i] = nullptr; srcB[i] = nullptr; }
        ldst[i] = row*72 + c8;
    }
    uint4 st0[2], st1[2];
#pragma unroll
    for (int i = 0; i < 2; ++i) {
        st0[i] = srcA0[i] ? *(const uint4*)(srcA0[i]) : make_uint4(0,0,0,0);
        st1[i] = srcA1[i] ? *(const uint4*)(srcA1[i]) : make_uint4(0,0,0,0);
    }

    f32x4 acc0[4] = {};
    f32x4 acc1[4] = {};
    const _Float16* wbH = WhP + (size_t)nt0*512 + lane*8;
    const _Float16* wbT = WtP + (size_t)nt0*512 + lane*8;
    int rowA = wave*16 + (lane & 15);
    int asub = (lane >> 4) << 3;

    for (int kc = 0; kc < 24; ++kc) {
        if (kc) __syncthreads();
        bool dual = (kc < 12);           // uniform branch
#pragma unroll
        for (int i = 0; i < 2; ++i) *(uint4*)(as0 + ldst[i]) = st0[i];
        if (dual) {
#pragma unroll
            for (int i = 0; i < 2; ++i) *(uint4*)(as1 + ldst[i]) = st1[i];
        }
        __syncthreads();
        int kn = kc + 1;
        if (kn < 24) {
            if (kn < 12) {
#pragma unroll
                for (int i = 0; i < 2; ++i) {
                    st0[i] = srcA0[i] ? *(const uint4*)(srcA0[i] + kn*64) : make_uint4(0,0,0,0);
                    st1[i] = srcA1[i] ? *(const uint4*)(srcA1[i] + kn*64) : make_uint4(0,0,0,0);
                }
            } else {
#pragma unroll
                for (int i = 0; i < 2; ++i)
                    st0[i] = srcB[i] ? *(const uint4*)(srcB[i] + (kn-12)*64) : make_uint4(0,0,0,0);
            }
        }
#pragma unroll
        for (int kk = 0; kk < 2; ++kk) {
            int kt = kc*2 + kk;
            const _Float16* wpH = wbH + (size_t)kt*(48*512);
            const _Float16* wpT = wbT + (size_t)kt*(48*512);
            f16x8 bfH[4], bfT[4];
#pragma unroll
            for (int jn = 0; jn < 4; ++jn) {
                bfH[jn] = *(const f16x8*)(wpH + jn*512);
                bfT[jn] = *(const f16x8*)(wpT + jn*512);
            }
            f16x8 af0 = *(const f16x8*)(as0 + rowA*72 + kk*32 + asub);
            f16x8 af1 = dual ? *(const f16x8*)(as1 + rowA*72 + kk*32 + asub) : af0;
#pragma unroll
            for (int jn = 0; jn < 4; ++jn) {
                acc0[jn] = __builtin_amdgcn_mfma_f32_16x16x32_f16(af0, bfH[jn], acc0[jn], 0, 0, 0);
                acc1[jn] = __builtin_amdgcn_mfma_f32_16x16x32_f16(af1, bfT[jn], acc1[jn], 0, 0, 0);
            }
        }
    }
    int crow = (lane >> 4) * 4;
    int ccol = lane & 15;
#pragma unroll
    for (int jn = 0; jn < 4; ++jn) {
        int n = nt0*16 + jn*16 + ccol;
        float bvh = bh[n], bvt = bt[n];
#pragma unroll
        for (int reg = 0; reg < 4; ++reg) {
            int r = r0 + wave*16 + crow + reg;
            if (r < R_) {
                zh[(size_t)r*H_ + n] = (_Float16)tanhf(acc0[jn][reg] + bvh);
                zt[(size_t)r*H_ + n] = (_Float16)tanhf(acc1[jn][reg] + bvt);
            }
        }
    }
}

// ---------------- K6: logits — BM=256, 4 waves, ms=4, S=48, fp16 part ------
__launch_bounds__(256, 2)
__global__ void k_logits_mfma(const _Float16* __restrict__ zh, const _Float16* __restrict__ zt,
                              const _Float16* __restrict__ WbP, _Float16* __restrict__ part) {
    __shared__ _Float16 zhs[256*20];   // 10 KB
    __shared__ _Float16 zts[256*72];   // 36.9 KB
    int bid = blockIdx.x;
    int xcd = bid & 7, j = bid >> 3;   // j 0..53
    int kc  = xcd*6 + j/9;             // 0..47
    int rt  = j % 9;
    int r0  = rt * 256;
    int g64 = (kc >> 2) * 64;          // zt col base
    int a0  = (kc & 3) * 16;           // zh col base within g

    for (int it = 0; it < 2; ++it) {
        int t = threadIdx.x + it*256;
        int row = t >> 1, i8 = (t & 1)*8;
        int r = r0 + row;
        uint4 w = make_uint4(0,0,0,0);
        if (r < R_) w = *(const uint4*)(zh + (size_t)r*H_ + g64 + a0 + i8);
        *(uint4*)(zhs + row*20 + i8) = w;
    }
    for (int it = 0; it < 8; ++it) {
        int t = threadIdx.x + it*256;
        int row = t >> 3, j8 = (t & 7)*8;
        int r = r0 + row;
        uint4 w = make_uint4(0,0,0,0);
        if (r < R_) w = *(const uint4*)(zt + (size_t)r*H_ + g64 + j8);
        *(uint4*)(zts + row*72 + j8) = w;
    }
    __syncthreads();

    int wave = threadIdx.x >> 6, lane = threadIdx.x & 63;
    int rowA0 = wave*64 + (lane & 15);    // wave covers 64 rows (ms=4)
    int jsub  = (lane >> 4) * 8;

    f32x4 acc[4][NTIL_] = {};
    const _Float16* wb0 = WbP + (size_t)(kc*32) * (NTIL_*512) + lane*8;

    f16x8 bf[NTIL_];
#pragma unroll
    for (int nt = 0; nt < NTIL_; ++nt) bf[nt] = *(const f16x8*)(wb0 + nt*512);

    for (int ktl = 0; ktl < 32; ++ktl) {
        f16x8 bn[NTIL_];
        if (ktl + 1 < 32) {
            const _Float16* wp = wb0 + (size_t)(ktl+1) * (NTIL_*512);
#pragma unroll
            for (int nt = 0; nt < NTIL_; ++nt) bn[nt] = *(const f16x8*)(wp + nt*512);
        }
        int il = ktl >> 1;
        int jb = (ktl & 1) * 32 + jsub;
#pragma unroll
        for (int ms = 0; ms < 4; ++ms) {
            int row = rowA0 + ms*16;
            _Float16 hv = zhs[row*20 + il];
            h2 hb = {hv, hv};
            union { uint4 u; h2 v[4]; } T;
            T.u = *(const uint4*)(zts + row*72 + jb);
            union { h2 v[4]; f16x8 f; } A;
            A.v[0] = hb * T.v[0];
            A.v[1] = hb * T.v[1];
            A.v[2] = hb * T.v[2];
            A.v[3] = hb * T.v[3];
#pragma unroll
            for (int nt = 0; nt < NTIL_; ++nt)
                acc[ms][nt] = __builtin_amdgcn_mfma_f32_16x16x32_f16(A.f, bf[nt], acc[ms][nt], 0, 0, 0);
        }
        if (ktl + 1 < 32) {
#pragma unroll
            for (int nt = 0; nt < NTIL_; ++nt) bf[nt] = bn[nt];
        }
    }

    int crow0 = wave*64 + (lane >> 4) * 4;
    int ccol  = lane & 15;
#pragma unroll
    for (int ms = 0; ms < 4; ++ms) {
#pragma unroll
        for (int nt = 0; nt < NTIL_; ++nt) {
#pragma unroll
            for (int reg = 0; reg < 4; ++reg) {
                int rp = r0 + crow0 + ms*16 + reg;
                part[((size_t)kc*PR2_ + rp)*112 + nt*16 + ccol] = (_Float16)acc[ms][nt][reg];
            }
        }
    }
}

// ---------------- K7: reduce fp16 partials + bias --------------------------
__global__ void k_logits_reduce(const _Float16* __restrict__ part, const float* __restrict__ bb,
                                float* __restrict__ out) {
    int idx = blockIdx.x*256 + threadIdx.x;
    if (idx >= R_*NL_) return;
    int r = idx / NL_, n = idx - r*NL_;
    float s = bb[n];
#pragma unroll
    for (int kc = 0; kc < S_; ++kc) s += (float)part[((size_t)kc*PR2_ + r)*112 + n];
    out[idx] = s;
}

extern "C" void kernel_launch(void* const* d_in, const int* in_sizes, int n_in,
                              void* d_out, int out_size, void* d_ws, size_t ws_size,
                              hipStream_t stream) {
    const float* seq   = (const float*)d_in[0];
    const float* att   = (const float*)d_in[1];
    const float* mmask = (const float*)d_in[2];
    const float* Wh    = (const float*)d_in[3];
    const float* bh    = (const float*)d_in[4];
    const float* Wt    = (const float*)d_in[5];
    const float* bt    = (const float*)d_in[6];
    const float* Wb    = (const float*)d_in[7];
    const float* bb    = (const float*)d_in[8];
    const int*   midx  = (const int*)d_in[9];
    const int*   hts   = (const int*)d_in[10];
    float* out = (float*)d_out;

    char* base = (char*)d_ws;
    _Float16* WbP  = (_Float16*)base;  base += (size_t)KT_*NTIL_*64*8 * 2;      // 11.0 MB
    _Float16* WhP  = (_Float16*)base;  base += (size_t)48*48*64*8 * 2;          //  2.4 MB
    _Float16* WtP  = (_Float16*)base;  base += (size_t)48*48*64*8 * 2;          //  2.4 MB
    _Float16* seqP = (_Float16*)base;  base += (size_t)B_*32*48*64*8 * 2;       //  6.3 MB
    _Float16* ee   = (_Float16*)base;  base += (size_t)B_*E_*H_ * 2;            //  0.15 MB
    _Float16* ea   = (_Float16*)base;  base += (size_t)B_*E_*NH_*L_ * 2;        //  2.4 MB
    _Float16* ht   = (_Float16*)base;  base += (size_t)R_*L_ * 2;               //  4.5 MB
    _Float16* rs   = (_Float16*)base;  base += (size_t)R_*H_ * 2;               //  3.4 MB
    _Float16* zh   = (_Float16*)base;  base += (size_t)R_*H_ * 2;               //  3.4 MB
    _Float16* zt   = (_Float16*)base;  base += (size_t)R_*H_ * 2;               //  3.4 MB
    _Float16* part = (_Float16*)base;                                           // 24.8 MB

    k_pack<<<dim3(PKB_ATT + PKB_WB + 2*PKB_W + PKB_SEQ + PKB_EMB), dim3(256), 0, stream>>>(
        att, Wb, Wh, Wt, seq, midx, mmask, ea, WbP, WhP, WtP, seqP, ee);

    k_ht_att<<<dim3(R_), dim3(128), 0, stream>>>(ea, hts, ht);

    k_rs_mfma<<<dim3(240), dim3(256), 0, stream>>>(ht, seqP, rs);

    k_z_mfma<<<dim3(216), dim3(512), 0, stream>>>(ee, rs, WhP, WtP, bh, bt, hts, zh, zt);

    k_logits_mfma  <<<dim3(432), dim3(256), 0, stream>>>(zh, zt, WbP, part);
    k_logits_reduce<<<dim3((R_*NL_ + 255)/256), dim3(256), 0, stream>>>(part, bb, out);
}

// Round 13
// 114.654 us; speedup vs baseline: 4.6857x; 1.0488x over previous
//
#include <hip/hip_runtime.h>
#include <math.h>

#define B_   4
#define L_   1024
#define H_   768
#define NH_  12
#define E_   24
#define M_   4
#define P_   552
#define NL_  97
#define H2_  1536          // 2*H
#define HB_  49152         // H*BLK
#define R_   2208          // B*P
#define NEG_ (-1e30f)

// logits MFMA tiling: BM=256 (4 waves x ms=4), 9 r-tiles, 48 K-chunks of 1024
#define RT2_  9
#define PR2_  2304         // RT2*256
#define S_    48
#define NTIL_ 7            // 112 padded cols / 16
#define KT_   1536         // HB/32 k-steps total

typedef _Float16 h2   __attribute__((ext_vector_type(2)));
typedef _Float16 f16x8 __attribute__((ext_vector_type(8)));
typedef float    f32x4 __attribute__((ext_vector_type(4)));

__device__ inline uint pkh(float lo, float hi) {      // fast RTZ pack
    union { __fp16 v __attribute__((ext_vector_type(2))); uint u; } c;
    c.v = __builtin_amdgcn_cvt_pkrtz(lo, hi);
    return c.u;
}
__device__ inline ushort h_rne(float x) {
    union { _Float16 h; ushort u; } c; c.h = (_Float16)x; return c.u;
}
__device__ inline uint h2_rne(float lo, float hi) {
    return (uint)h_rne(lo) | ((uint)h_rne(hi) << 16);
}

// ---------------- fused pack + ent_att + ent_emb ---------------------------
#define PKB_ATT 1152
#define PKB_WB  2688
#define PKB_W   576      // 48kt*48nt*64lane = 147456 = 576*256 EXACT
#define PKB_SEQ 1536
#define PKB_EMB 96
__global__ void k_pack(const float* __restrict__ att, const float* __restrict__ Wb,
                       const float* __restrict__ Wh, const float* __restrict__ Wt,
                       const float* __restrict__ seq,
                       const int* __restrict__ midx, const float* __restrict__ mmask,
                       _Float16* __restrict__ ea, _Float16* __restrict__ WbP,
                       _Float16* __restrict__ WhP, _Float16* __restrict__ WtP,
                       _Float16* __restrict__ seqP, _Float16* __restrict__ ee) {
    int bid = blockIdx.x;
    if (bid < PKB_ATT) {                    // entity_atts -> fp16 (float4 loads)
        int n  = bid % NH_;
        int be = bid / NH_;
        int b  = be / E_;
        int idx[M_]; float msk[M_]; float denom = 0.f;
#pragma unroll
        for (int m = 0; m < M_; ++m) { idx[m] = midx[be*M_+m]; msk[m] = mmask[be*M_+m]; denom += msk[m]; }
        float inv = 1.f / denom;
        const float* abase = att + (size_t)(b*NH_ + n) * L_ * L_;
        int l4 = threadIdx.x * 4;           // 256 threads x 4 = 1024
        float s0 = 0.f, s1 = 0.f, s2 = 0.f, s3 = 0.f;
#pragma unroll
        for (int m = 0; m < M_; ++m) {
            float4 a = *(const float4*)(abase + idx[m]*L_ + l4);
            s0 += msk[m]*a.x; s1 += msk[m]*a.y; s2 += msk[m]*a.z; s3 += msk[m]*a.w;
        }
        *(uint2*)(ea + (((size_t)(be*NH_ + n)) << 10) + l4) =
            make_uint2(pkh(s0*inv, s1*inv), pkh(s2*inv, s3*inv));
        return;
    }
    if (bid < PKB_ATT + PKB_WB) {           // Wb -> [kt][nt][lane][8]
        int t = (bid - PKB_ATT)*256 + threadIdx.x;
        int lane = t & 63;
        int nt   = (t >> 6) % NTIL_;
        int kt   = t / (NTIL_*64);
        int n = nt*16 + (lane & 15);
        int k = kt*32 + ((lane >> 4) << 3);
        uint w[4] = {0u,0u,0u,0u};
        if (n < NL_) {
            const float* src = Wb + (size_t)n*HB_ + k;
#pragma unroll
            for (int e = 0; e < 4; ++e) w[e] = h2_rne(src[2*e], src[2*e+1]);
        }
        *(uint4*)(WbP + (size_t)t*8) = make_uint4(w[0],w[1],w[2],w[3]);
        return;
    }
    if (bid < PKB_ATT + PKB_WB + 2*PKB_W) { // Wh / Wt -> [kt][nt][lane][8]
        int seg = bid - PKB_ATT - PKB_WB;
        const float* W = (seg < PKB_W) ? Wh : Wt;
        _Float16*   WP = (seg < PKB_W) ? WhP : WtP;
        int t = (seg % PKB_W)*256 + threadIdx.x;
        int lane = t & 63;
        int nt   = (t >> 6) % 48;
        int kt   = t / (48*64);
        int n = nt*16 + (lane & 15);
        int k = kt*32 + ((lane >> 4) << 3);
        const float* src = W + (size_t)n*H2_ + k;
        uint w[4];
#pragma unroll
        for (int e = 0; e < 4; ++e) w[e] = h2_rne(src[2*e], src[2*e+1]);
        *(uint4*)(WP + (size_t)t*8) = make_uint4(w[0],w[1],w[2],w[3]);
        return;
    }
    if (bid < PKB_ATT + PKB_WB + 2*PKB_W + PKB_SEQ) {   // seq -> per-b frag
        int t = (bid - PKB_ATT - PKB_WB - 2*PKB_W)*256 + threadIdx.x;
        int lane = t & 63;
        int rest = t >> 6;
        int nt = rest % 48; rest /= 48;
        int kt = rest % 32;
        int b  = rest / 32;
        int n = nt*16 + (lane & 15);
        int k = kt*32 + ((lane >> 4) << 3);
        const float* src = seq + ((size_t)(b*L_ + k))*H_ + n;
        uint w[4];
#pragma unroll
        for (int e = 0; e < 4; ++e) w[e] = h2_rne(src[(2*e)*H_], src[(2*e+1)*H_]);
        *(uint4*)(seqP + (size_t)t*8) = make_uint4(w[0],w[1],w[2],w[3]);
        return;
    }
    // ent_emb: logsumexp over mentions -> fp16
    int be = bid - (PKB_ATT + PKB_WB + 2*PKB_W + PKB_SEQ);
    int b  = be / E_;
    int idx[M_]; float msk[M_];
#pragma unroll
    for (int m = 0; m < M_; ++m) { idx[m] = midx[be*M_+m]; msk[m] = mmask[be*M_+m]; }
    for (int d = threadIdx.x; d < H_; d += 256) {
        float v[M_]; float mx = NEG_;
#pragma unroll
        for (int m = 0; m < M_; ++m) {
            v[m] = (msk[m] > 0.f) ? seq[(b*L_ + idx[m])*H_ + d] : NEG_;
            mx = fmaxf(mx, v[m]);
        }
        float s = 0.f;
#pragma unroll
        for (int m = 0; m < M_; ++m) s += expf(v[m] - mx);
        ee[be*H_ + d] = (_Float16)(mx + logf(s));
    }
}

// ---------------- K3: ht_att (128 threads, 16B loads) ----------------------
__global__ void k_ht_att(const _Float16* __restrict__ ea, const int* __restrict__ hts,
                         _Float16* __restrict__ ht) {
    __shared__ float red[2];
    int bp = blockIdx.x;            // b*P+p
    int b  = bp / P_;
    int h = hts[bp*2+0], t = hts[bp*2+1];
    const uint4* eh4 = (const uint4*)(ea + ((size_t)(b*E_ + h)*NH_ << 10));
    const uint4* et4 = (const uint4*)(ea + ((size_t)(b*E_ + t)*NH_ << 10));
    int lp = threadIdx.x;           // 0..127, each covers l = lp*8..+7
    float s[8] = {};
#pragma unroll
    for (int n = 0; n < NH_; ++n) {
        union { uint4 u; h2 v[4]; } A, C;
        A.u = eh4[n*128 + lp];
        C.u = et4[n*128 + lp];
#pragma unroll
        for (int q = 0; q < 4; ++q) {
            s[2*q]   += (float)A.v[q][0]*(float)C.v[q][0];
            s[2*q+1] += (float)A.v[q][1]*(float)C.v[q][1];
        }
    }
    float local = 0.f;
#pragma unroll
    for (int q = 0; q < 8; ++q) { s[q] *= (1.f/NH_); local += s[q]; }
#pragma unroll
    for (int o = 32; o > 0; o >>= 1) local += __shfl_down(local, o);
    int wid = threadIdx.x >> 6, lane = threadIdx.x & 63;
    if (lane == 0) red[wid] = local;
    __syncthreads();
    if (threadIdx.x == 0) red[0] = 1.f / (red[0] + red[1] + 1e-5f);
    __syncthreads();
    float inv = red[0];
    *(uint4*)(ht + ((size_t)bp << 10) + lp*8) =
        make_uint4(pkh(s[0]*inv, s[1]*inv), pkh(s[2]*inv, s[3]*inv),
                   pkh(s[4]*inv, s[5]*inv), pkh(s[6]*inv, s[7]*inv));
}

// ---------------- K4: rs = ht @ seq, BM=128 (ms=2), XCD-pinned b -----------
// flat grid 240: xcd=bid&7 -> b=xcd>>1; tile=(xcd&1)*30+(bid>>3): 5pt x 12nt
__launch_bounds__(256, 2)
__global__ void k_rs_mfma(const _Float16* __restrict__ ht, const _Float16* __restrict__ seqP,
                          _Float16* __restrict__ rs) {
    __shared__ _Float16 as[128*72];
    int bid = blockIdx.x;
    int xcd = bid & 7, jj0 = bid >> 3;   // jj0 0..29
    int b    = xcd >> 1;
    int tile = (xcd & 1)*30 + jj0;       // 0..59
    int p0   = (tile % 5) * 128;
    int nt0  = (tile / 5) * 4;
    int wave = threadIdx.x >> 6, lane = threadIdx.x & 63;

    const _Float16* srcp[4];
    int ldst[4];
#pragma unroll
    for (int i = 0; i < 4; ++i) {
        int t = threadIdx.x + i*256;
        int row = t >> 3, c8 = (t & 7)*8;
        int p = p0 + row;
        srcp[i] = (p < P_) ? ht + (((size_t)(b*P_ + p)) << 10) + c8 : nullptr;
        ldst[i] = row*72 + c8;
    }
    uint4 st[4];
#pragma unroll
    for (int i = 0; i < 4; ++i)
        st[i] = srcp[i] ? *(const uint4*)(srcp[i]) : make_uint4(0,0,0,0);

    f32x4 acc[2][4] = {};
    const _Float16* wbase = seqP + ((size_t)b*32*48 + nt0)*512 + lane*8;
    int rowbase = wave*32 + (lane & 15);
    int asub = (lane >> 4) << 3;

    for (int kc = 0; kc < 16; ++kc) {
        if (kc) __syncthreads();
#pragma unroll
        for (int i = 0; i < 4; ++i) *(uint4*)(as + ldst[i]) = st[i];
        __syncthreads();
        if (kc + 1 < 16) {
#pragma unroll
            for (int i = 0; i < 4; ++i)
                st[i] = srcp[i] ? *(const uint4*)(srcp[i] + (kc+1)*64) : make_uint4(0,0,0,0);
        }
#pragma unroll
        for (int kk = 0; kk < 2; ++kk) {
            int kt = kc*2 + kk;
            const _Float16* wp = wbase + (size_t)kt*(48*512);
            f16x8 bf[4];
#pragma unroll
            for (int jn = 0; jn < 4; ++jn) bf[jn] = *(const f16x8*)(wp + jn*512);
#pragma unroll
            for (int ms = 0; ms < 2; ++ms) {
                f16x8 af = *(const f16x8*)(as + (rowbase + ms*16)*72 + kk*32 + asub);
#pragma unroll
                for (int jn = 0; jn < 4; ++jn)
                    acc[ms][jn] = __builtin_amdgcn_mfma_f32_16x16x32_f16(af, bf[jn], acc[ms][jn], 0, 0, 0);
            }
        }
    }
    int crow = (lane >> 4) * 4;
    int ccol = lane & 15;
#pragma unroll
    for (int ms = 0; ms < 2; ++ms) {
#pragma unroll
        for (int jn = 0; jn < 4; ++jn) {
            int n = nt0*16 + jn*16 + ccol;
#pragma unroll
            for (int reg = 0; reg < 4; ++reg) {
                int p = p0 + wave*32 + ms*16 + crow + reg;
                if (p < P_) rs[(size_t)(b*P_ + p)*H_ + n] = (_Float16)acc[ms][jn][reg];
            }
        }
    }
}

// ---------------- K5: zh & zt, BM=128 (ms=2), XCD-pinned which -------------
// flat grid 432: xcd=bid&7 -> which=xcd>>2; tile=(xcd&3)*54+(bid>>3): 18rt x 12nt
__launch_bounds__(256, 2)
__global__ void k_z_mfma(const _Float16* __restrict__ ee, const _Float16* __restrict__ rs,
                         const _Float16* __restrict__ WhP, const _Float16* __restrict__ WtP,
                         const float* __restrict__ bh, const float* __restrict__ bt,
                         const int* __restrict__ hts,
                         _Float16* __restrict__ zh, _Float16* __restrict__ zt) {
    __shared__ _Float16 as[128*72];
    int bid = blockIdx.x;
    int xcd = bid & 7, jj0 = bid >> 3;   // jj0 0..53
    int which = xcd >> 2;
    int tile  = (xcd & 3)*54 + jj0;      // 0..215
    int r0  = (tile % 18) * 128;
    int nt0 = (tile / 18) * 4;
    const _Float16* WP   = which ? WtP : WhP;
    const float*    bias = which ? bt  : bh;
    _Float16*       out  = which ? zt  : zh;
    int wave = threadIdx.x >> 6, lane = threadIdx.x & 63;

    const _Float16* srcA[4];
    const _Float16* srcB[4];
    int ldst[4];
#pragma unroll
    for (int i = 0; i < 4; ++i) {
        int t = threadIdx.x + i*256;
        int row = t >> 3, c8 = (t & 7)*8;
        int r = r0 + row;
        if (r < R_) {
            int b = r / P_;
            int eidx = hts[r*2 + which];
            srcA[i] = ee + (size_t)(b*E_ + eidx)*H_ + c8;
            srcB[i] = rs + (size_t)r*H_ + c8;
        } else { srcA[i] = nullptr; srcB[i] = nullptr; }
        ldst[i] = row*72 + c8;
    }
    uint4 st[4];
#pragma unroll
    for (int i = 0; i < 4; ++i)
        st[i] = srcA[i] ? *(const uint4*)(srcA[i]) : make_uint4(0,0,0,0);

    f32x4 acc[2][4] = {};
    const _Float16* wbase = WP + (size_t)nt0*512 + lane*8;
    int rowbase = wave*32 + (lane & 15);
    int asub = (lane >> 4) << 3;

    for (int kc = 0; kc < 24; ++kc) {
        if (kc) __syncthreads();
#pragma unroll
        for (int i = 0; i < 4; ++i) *(uint4*)(as + ldst[i]) = st[i];
        __syncthreads();
        if (kc + 1 < 24) {
            int kn = kc + 1;
#pragma unroll
            for (int i = 0; i < 4; ++i) {
                const _Float16* s = (kn < 12) ? (srcA[i] ? srcA[i] + kn*64 : nullptr)
                                              : (srcB[i] ? srcB[i] + (kn-12)*64 : nullptr);
                st[i] = s ? *(const uint4*)s : make_uint4(0,0,0,0);
            }
        }
#pragma unroll
        for (int kk = 0; kk < 2; ++kk) {
            int kt = kc*2 + kk;
            const _Float16* wp = wbase + (size_t)kt*(48*512);
            f16x8 bf[4];
#pragma unroll
            for (int jn = 0; jn < 4; ++jn) bf[jn] = *(const f16x8*)(wp + jn*512);
#pragma unroll
            for (int ms = 0; ms < 2; ++ms) {
                f16x8 af = *(const f16x8*)(as + (rowbase + ms*16)*72 + kk*32 + asub);
#pragma unroll
                for (int jn = 0; jn < 4; ++jn)
                    acc[ms][jn] = __builtin_amdgcn_mfma_f32_16x16x32_f16(af, bf[jn], acc[ms][jn], 0, 0, 0);
            }
        }
    }
    int crow = (lane >> 4) * 4;
    int ccol = lane & 15;
#pragma unroll
    for (int ms = 0; ms < 2; ++ms) {
#pragma unroll
        for (int jn = 0; jn < 4; ++jn) {
            int n = nt0*16 + jn*16 + ccol;
            float bv = bias[n];
#pragma unroll
            for (int reg = 0; reg < 4; ++reg) {
                int r = r0 + wave*32 + ms*16 + crow + reg;
                if (r < R_) out[(size_t)r*H_ + n] = (_Float16)tanhf(acc[ms][jn][reg] + bv);
            }
        }
    }
}

// ---------------- K6: logits — BM=256, 4 waves, ms=4, S=48, fp16 part ------
// flat grid 432: xcd=bid&7 -> kc = xcd*6 + j/9 (6 kc per XCD, 1.4MB L2); rt=j%9
__launch_bounds__(256, 2)
__global__ void k_logits_mfma(const _Float16* __restrict__ zh, const _Float16* __restrict__ zt,
                              const _Float16* __restrict__ WbP, _Float16* __restrict__ part) {
    __shared__ _Float16 zhs[256*20];   // 10 KB (16 i-cols + pad)
    __shared__ _Float16 zts[256*72];   // 36.9 KB
    int bid = blockIdx.x;
    int xcd = bid & 7, j = bid >> 3;   // j 0..53
    int kc  = xcd*6 + j/9;             // 0..47
    int rt  = j % 9;
    int r0  = rt * 256;
    int g64 = (kc >> 2) * 64;          // zt col base (g block)
    int a0  = (kc & 3) * 16;           // zh col base within g

    for (int it = 0; it < 2; ++it) {
        int t = threadIdx.x + it*256;  // 0..511
        int row = t >> 1, i8 = (t & 1)*8;
        int r = r0 + row;
        uint4 w = make_uint4(0,0,0,0);
        if (r < R_) w = *(const uint4*)(zh + (size_t)r*H_ + g64 + a0 + i8);
        *(uint4*)(zhs + row*20 + i8) = w;
    }
    for (int it = 0; it < 8; ++it) {
        int t = threadIdx.x + it*256;  // 0..2047
        int row = t >> 3, j8 = (t & 7)*8;
        int r = r0 + row;
        uint4 w = make_uint4(0,0,0,0);
        if (r < R_) w = *(const uint4*)(zt + (size_t)r*H_ + g64 + j8);
        *(uint4*)(zts + row*72 + j8) = w;
    }
    __syncthreads();

    int wave = threadIdx.x >> 6, lane = threadIdx.x & 63;
    int rowA0 = wave*64 + (lane & 15);    // wave covers 64 rows (ms=4)
    int jsub  = (lane >> 4) * 8;

    f32x4 acc[4][NTIL_] = {};
    const _Float16* wb0 = WbP + (size_t)(kc*32) * (NTIL_*512) + lane*8;

    f16x8 bf[NTIL_];
#pragma unroll
    for (int nt = 0; nt < NTIL_; ++nt) bf[nt] = *(const f16x8*)(wb0 + nt*512);

    for (int ktl = 0; ktl < 32; ++ktl) {
        f16x8 bn[NTIL_];
        if (ktl + 1 < 32) {
            const _Float16* wp = wb0 + (size_t)(ktl+1) * (NTIL_*512);
#pragma unroll
            for (int nt = 0; nt < NTIL_; ++nt) bn[nt] = *(const f16x8*)(wp + nt*512);
        }
        int il = ktl >> 1;
        int jb = (ktl & 1) * 32 + jsub;
#pragma unroll
        for (int ms = 0; ms < 4; ++ms) {
            int row = rowA0 + ms*16;
            _Float16 hv = zhs[row*20 + il];
            h2 hb = {hv, hv};
            union { uint4 u; h2 v[4]; } T;
            T.u = *(const uint4*)(zts + row*72 + jb);
            union { h2 v[4]; f16x8 f; } A;
            A.v[0] = hb * T.v[0];
            A.v[1] = hb * T.v[1];
            A.v[2] = hb * T.v[2];
            A.v[3] = hb * T.v[3];
#pragma unroll
            for (int nt = 0; nt < NTIL_; ++nt)
                acc[ms][nt] = __builtin_amdgcn_mfma_f32_16x16x32_f16(A.f, bf[nt], acc[ms][nt], 0, 0, 0);
        }
        if (ktl + 1 < 32) {
#pragma unroll
            for (int nt = 0; nt < NTIL_; ++nt) bf[nt] = bn[nt];
        }
    }

    int crow0 = wave*64 + (lane >> 4) * 4;
    int ccol  = lane & 15;
#pragma unroll
    for (int ms = 0; ms < 4; ++ms) {
#pragma unroll
        for (int nt = 0; nt < NTIL_; ++nt) {
#pragma unroll
            for (int reg = 0; reg < 4; ++reg) {
                int rp = r0 + crow0 + ms*16 + reg;
                part[((size_t)kc*PR2_ + rp)*112 + nt*16 + ccol] = (_Float16)acc[ms][nt][reg];
            }
        }
    }
}

// ---------------- K7: reduce fp16 partials + bias --------------------------
__global__ void k_logits_reduce(const _Float16* __restrict__ part, const float* __restrict__ bb,
                                float* __restrict__ out) {
    int idx = blockIdx.x*256 + threadIdx.x;
    if (idx >= R_*NL_) return;
    int r = idx / NL_, n = idx - r*NL_;
    float s = bb[n];
#pragma unroll
    for (int kc = 0; kc < S_; ++kc) s += (float)part[((size_t)kc*PR2_ + r)*112 + n];
    out[idx] = s;
}

extern "C" void kernel_launch(void* const* d_in, const int* in_sizes, int n_in,
                              void* d_out, int out_size, void* d_ws, size_t ws_size,
                              hipStream_t stream) {
    const float* seq   = (const float*)d_in[0];
    const float* att   = (const float*)d_in[1];
    const float* mmask = (const float*)d_in[2];
    const float* Wh    = (const float*)d_in[3];
    const float* bh    = (const float*)d_in[4];
    const float* Wt    = (const float*)d_in[5];
    const float* bt    = (const float*)d_in[6];
    const float* Wb    = (const float*)d_in[7];
    const float* bb    = (const float*)d_in[8];
    const int*   midx  = (const int*)d_in[9];
    const int*   hts   = (const int*)d_in[10];
    float* out = (float*)d_out;

    char* base = (char*)d_ws;
    _Float16* WbP  = (_Float16*)base;  base += (size_t)KT_*NTIL_*64*8 * 2;      // 11.0 MB
    _Float16* WhP  = (_Float16*)base;  base += (size_t)48*48*64*8 * 2;          //  2.4 MB
    _Float16* WtP  = (_Float16*)base;  base += (size_t)48*48*64*8 * 2;          //  2.4 MB
    _Float16* seqP = (_Float16*)base;  base += (size_t)B_*32*48*64*8 * 2;       //  6.3 MB
    _Float16* ee   = (_Float16*)base;  base += (size_t)B_*E_*H_ * 2;            //  0.15 MB
    _Float16* ea   = (_Float16*)base;  base += (size_t)B_*E_*NH_*L_ * 2;        //  2.4 MB
    _Float16* ht   = (_Float16*)base;  base += (size_t)R_*L_ * 2;               //  4.5 MB
    _Float16* rs   = (_Float16*)base;  base += (size_t)R_*H_ * 2;               //  3.4 MB
    _Float16* zh   = (_Float16*)base;  base += (size_t)R_*H_ * 2;               //  3.4 MB
    _Float16* zt   = (_Float16*)base;  base += (size_t)R_*H_ * 2;               //  3.4 MB
    _Float16* part = (_Float16*)base;                                           // 24.8 MB

    k_pack<<<dim3(PKB_ATT + PKB_WB + 2*PKB_W + PKB_SEQ + PKB_EMB), dim3(256), 0, stream>>>(
        att, Wb, Wh, Wt, seq, midx, mmask, ea, WbP, WhP, WtP, seqP, ee);

    k_ht_att<<<dim3(R_), dim3(128), 0, stream>>>(ea, hts, ht);

    k_rs_mfma<<<dim3(240), dim3(256), 0, stream>>>(ht, seqP, rs);

    k_z_mfma<<<dim3(432), dim3(256), 0, stream>>>(ee, rs, WhP, WtP, bh, bt, hts, zh, zt);

    k_logits_mfma  <<<dim3(432), dim3(256), 0, stream>>>(zh, zt, WbP, part);
    k_logits_reduce<<<dim3((R_*NL_ + 255)/256), dim3(256), 0, stream>>>(part, bb, out);
}